// Round 31
// baseline (5405.810 us; speedup 1.0000x reference)
//
#include <hip/hip_runtime.h>

#define LOG2E 1.44269504088896340736f

typedef float v2f __attribute__((ext_vector_type(2)));

__device__ __forceinline__ float lrelu(float z) { return fmaxf(z, 0.01f * z); }
__device__ __forceinline__ float sigf(float z) {
    float p = __builtin_amdgcn_exp2f(-LOG2E * z);
    return __builtin_amdgcn_rcpf(1.0f + p);
}
__device__ __forceinline__ v2f fma2(v2f a, float w, v2f c) {
    return __builtin_elementwise_fma(a, (v2f)(w), c);   // -> v_pk_fma_f32
}
__device__ __forceinline__ v2f lrelu2(v2f z) {
    return __builtin_elementwise_max(z, z * 0.01f);     // -> v_pk_max/mul
}
__device__ __forceinline__ v2f sig2(v2f z) {
    v2f r; r.x = sigf(z.x); r.y = sigf(z.y); return r;  // scalar trans
}

#define WQ(i) __int_as_float(__builtin_amdgcn_readlane(__float_as_int(wreg[(i) >> 6]), (i) & 63))

// ====== PC-v11: pc8 exactly, A/B points packed into v2f -> v_pk_fma_f32 ====
// R30: X-batching regressed; schedule levers exhausted; pc8=3.53ms floor with
// scalar fma. pc8's 2-pt/thread shape is ideal for CDNA's packed dual-fp32
// FMA: {accA,accB} = pk_fma({akA,akB}, splat(w), acc) halves the dominant
// instruction class (2000->1000 fma/wave-step). ext_vector+elementwise_fma
// emits llvm.fma.v2f32 -> v_pk_fma_f32. Bit-identical math (IEEE fma/half,
// same order) -> absmax 0. Everything else byte-identical to pc8.
__global__ void __launch_bounds__(256, 1)
pc11_kernel(const float* __restrict__ w,
            const float* __restrict__ Wh1, const float* __restrict__ bh1,
            const float* __restrict__ Wh2, const float* __restrict__ bh2,
            const float* __restrict__ Wh3, const float* __restrict__ bh3,
            const float* __restrict__ Wx1, const float* __restrict__ bx1,
            const float* __restrict__ Wx2, const float* __restrict__ bx2,
            const float* __restrict__ Wx3, const float* __restrict__ bx3,
            float2* __restrict__ out, int B, int T)
{
    __shared__ float4 sW2h[185];       // Wh2 rows 0..36
    __shared__ float4 sW2x[195];       // Wx2 rows 0..38
    __shared__ float2 hbuf[2][256];    // double-buffered h handoff

    {
        float* a = (float*)sW2h;
        for (int i = threadIdx.x; i < 740; i += 256) a[i] = Wh2[i];
        float* b = (float*)sW2x;
        for (int i = threadIdx.x; i < 780; i += 256) b[i] = Wx2[i];
    }

    const int wid  = threadIdx.x >> 6;     // 0..3
    const int lane = threadIdx.x & 63;
    const bool is_f = (wid < 2);

    float wreg[6];
    float wv[140];   // partial VGPR pin (R25/pc8 mechanism)
    if (is_f) {
#pragma unroll
        for (int r = 0; r < 6; ++r) {
            const int idx = r * 64 + lane;
            float v = 0.f;
            if      (idx < 100) v = Wh1[idx];
            else if (idx < 150) v = bh1[idx - 100];
            else if (idx < 270) v = Wh2[880 + (idx - 150)];   // rows 44..49
            else if (idx < 290) v = bh2[idx - 270];
            else if (idx < 330) v = Wh3[idx - 290];
            else if (idx < 332) v = bh3[idx - 330];
            wreg[r] = v;
        }
#pragma unroll
        for (int i = 0; i < 140; ++i) {        // pin Wh2 rows 37..43
            wv[i] = Wh2[740 + i];
            asm volatile("" : "+v"(wv[i]));
        }
    } else {
#pragma unroll
        for (int r = 0; r < 6; ++r) {
            const int idx = r * 64 + lane;
            float v = 0.f;
            if      (idx < 100) v = Wx1[idx];
            else if (idx < 150) v = bx1[idx - 100];
            else if (idx < 230) v = Wx2[920 + (idx - 150)];   // rows 46..49
            else if (idx < 250) v = bx2[idx - 230];
            else if (idx < 290) v = Wx3[idx - 250];
            else if (idx < 292) v = bx3[idx - 290];
            wreg[r] = v;
        }
#pragma unroll
        for (int i = 0; i < 140; ++i) {        // pin Wx2 rows 39..45
            wv[i] = Wx2[780 + i];
            asm volatile("" : "+v"(wv[i]));
        }
    }
    __syncthreads();

    const int lw = is_f ? wid : (wid - 2);
    const int lpA = lw * 128 + lane;
    const int lpB = lpA + 64;
    const int pA  = blockIdx.x * 256 + lpA;
    const int pB  = blockIdx.x * 256 + lpB;

    // packed recurrent state: .x = point A, .y = point B
    v2f H0 = (v2f)(0.f), H1 = (v2f)(0.f);
    if (is_f) {
        H0.x = w[2 * pA];     H0.y = w[2 * pB];
        H1.x = w[2 * pA + 1]; H1.y = w[2 * pB + 1];
    }
    float2* __restrict__ orowA = out + (size_t)pA * (size_t)T;
    float2* __restrict__ orowB = out + (size_t)pB * (size_t)T;

    for (int t = 0; t <= T; ++t) {
        if (is_f) {
            if (t < T) {
                // ===== F: h = lrelu3(h), packed A/B =====
                v2f a1[50];
#pragma unroll
                for (int j = 0; j < 50; ++j) {
                    const float s0 = WQ(j), s1 = WQ(50 + j), sb = WQ(100 + j);
                    a1[j] = lrelu2(fma2(H0, s0, fma2(H1, s1, (v2f)(sb))));
                }
                v2f acc[20];
#pragma unroll
                for (int c = 0; c < 20; ++c) acc[c] = (v2f)(WQ(270 + c));
#pragma unroll
                for (int k = 0; k < 37; ++k) {          // rows 0..36 via LDS
                    const v2f ak = a1[k];
#pragma unroll
                    for (int c = 0; c < 5; ++c) {
                        const float4 v = sW2h[k * 5 + c];
                        acc[4*c+0] = fma2(ak, v.x, acc[4*c+0]);
                        acc[4*c+1] = fma2(ak, v.y, acc[4*c+1]);
                        acc[4*c+2] = fma2(ak, v.z, acc[4*c+2]);
                        acc[4*c+3] = fma2(ak, v.w, acc[4*c+3]);
                    }
                }
#pragma unroll
                for (int k = 37; k < 44; ++k) {         // rows 37..43 via pin
                    const v2f ak = a1[k];
#pragma unroll
                    for (int c = 0; c < 20; ++c)
                        acc[c] = fma2(ak, wv[(k - 37) * 20 + c], acc[c]);
                }
#pragma unroll
                for (int k = 44; k < 50; ++k) {         // rows 44..49 via RL
                    const v2f ak = a1[k];
#pragma unroll
                    for (int c = 0; c < 20; ++c)
                        acc[c] = fma2(ak, WQ(150 + (k - 44) * 20 + c), acc[c]);
                }
                v2f z0 = (v2f)(WQ(330)), z1 = (v2f)(WQ(331));
#pragma unroll
                for (int k = 0; k < 20; ++k) {
                    const float wx = WQ(290 + 2 * k), wy = WQ(291 + 2 * k);
                    const v2f e = lrelu2(acc[k]);
                    z0 = fma2(e, wx, z0);
                    z1 = fma2(e, wy, z1);
                }
                H0 = lrelu2(z0); H1 = lrelu2(z1);

                hbuf[t & 1][lpA] = make_float2(H0.x, H1.x);
                hbuf[t & 1][lpB] = make_float2(H0.y, H1.y);
            }
        } else {
            if (t > 0) {
                // ===== X: x_s = sig3(h_s), s = t-1, packed A/B =====
                const int s = t - 1;
                const float2 hvA = hbuf[s & 1][lpA];
                const float2 hvB = hbuf[s & 1][lpB];
                v2f hx0; hx0.x = hvA.x; hx0.y = hvB.x;
                v2f hx1; hx1.x = hvA.y; hx1.y = hvB.y;

                v2f acc[20];
#pragma unroll
                for (int c = 0; c < 20; ++c) acc[c] = (v2f)(WQ(230 + c));
#pragma unroll
                for (int k = 0; k < 50; ++k) {
                    const float s0 = WQ(k), s1 = WQ(50 + k), sb = WQ(100 + k);
                    const v2f xk = sig2(fma2(hx0, s0, fma2(hx1, s1, (v2f)(sb))));
                    if (k < 39) {                        // rows 0..38 via LDS
#pragma unroll
                        for (int c = 0; c < 5; ++c) {
                            const float4 v = sW2x[k * 5 + c];
                            acc[4*c+0] = fma2(xk, v.x, acc[4*c+0]);
                            acc[4*c+1] = fma2(xk, v.y, acc[4*c+1]);
                            acc[4*c+2] = fma2(xk, v.z, acc[4*c+2]);
                            acc[4*c+3] = fma2(xk, v.w, acc[4*c+3]);
                        }
                    } else if (k < 46) {                 // rows 39..45 via pin
#pragma unroll
                        for (int c = 0; c < 20; ++c)
                            acc[c] = fma2(xk, wv[(k - 39) * 20 + c], acc[c]);
                    } else {                             // rows 46..49 via RL
#pragma unroll
                        for (int c = 0; c < 20; ++c)
                            acc[c] = fma2(xk, WQ(150 + (k - 46) * 20 + c), acc[c]);
                    }
                }
                v2f z0 = (v2f)(WQ(290)), z1 = (v2f)(WQ(291));
#pragma unroll
                for (int k = 0; k < 20; ++k) {
                    const float wx = WQ(250 + 2 * k), wy = WQ(251 + 2 * k);
                    const v2f e = sig2(acc[k]);
                    z0 = fma2(e, wx, z0);
                    z1 = fma2(e, wy, z1);
                }
                orowA[s] = make_float2(sigf(z0.x), sigf(z1.x));
                orowB[s] = make_float2(sigf(z0.y), sigf(z1.y));
            }
        }
        __syncthreads();   // orders hbuf write (iter t) -> read (iter t+1)
    }
}

extern "C" void kernel_launch(void* const* d_in, const int* in_sizes, int n_in,
                              void* d_out, int out_size, void* d_ws, size_t ws_size,
                              hipStream_t stream)
{
    const float* w   = (const float*)d_in[0];
    const float* Wh1 = (const float*)d_in[1];
    const float* bh1 = (const float*)d_in[2];
    const float* Wh2 = (const float*)d_in[3];
    const float* bh2 = (const float*)d_in[4];
    const float* Wh3 = (const float*)d_in[5];
    const float* bh3 = (const float*)d_in[6];
    const float* Wx1 = (const float*)d_in[7];
    const float* bx1 = (const float*)d_in[8];
    const float* Wx2 = (const float*)d_in[9];
    const float* bx2 = (const float*)d_in[10];
    const float* Wx3 = (const float*)d_in[11];
    const float* bx3 = (const float*)d_in[12];

    const int B = in_sizes[0] / 2;        // 65536 (divisible by 256)
    const int T = out_size / (B * 2);     // 512

    pc11_kernel<<<B / 256, 256, 0, stream>>>(
        w, Wh1, bh1, Wh2, bh2, Wh3, bh3,
        Wx1, bx1, Wx2, bx2, Wx3, bx3,
        (float2*)d_out, B, T);
}